// Round 6
// baseline (612.085 us; speedup 1.0000x reference)
//
#include <hip/hip_runtime.h>

// Problem constants (reference: N=65536, D=512, S=262144)
#define NROWS 65536
#define DCOLS 512
#define D4    128   // float4 per row
#define CHUNK 256   // rows per chunk
#define NCHUNK (NROWS / CHUNK)  // 256 chunks

typedef float f32x4 __attribute__((ext_vector_type(4)));

// ---------------------------------------------------------------------------
// Workspace layout (ints):
//   [0   .. 255]  chunksum[256]
//   [256 .. 511]  chunkoff[256]  (exclusive prefix of chunksum)
//   [512]         total
//   [768 .. ]     idx[S] (int, 1 MiB)
// ---------------------------------------------------------------------------

// K1: per-chunk sums of rep. 256 blocks x 256 threads. (settled in r5)
__global__ __launch_bounds__(256) void chunk_sum_kernel(const int* __restrict__ rep,
                                                        int* __restrict__ chunksum) {
    const int b = blockIdx.x;
    const int t = threadIdx.x;
    int v = rep[b * CHUNK + t];
#pragma unroll
    for (int off = 32; off; off >>= 1) v += __shfl_down(v, off);
    __shared__ int ws4[4];
    if ((t & 63) == 0) ws4[t >> 6] = v;
    __syncthreads();
    if (t == 0) chunksum[b] = ws4[0] + ws4[1] + ws4[2] + ws4[3];
}

// K2: exclusive scan of 256 chunk sums + total. One tiny block. (settled in r5)
__global__ __launch_bounds__(256) void scan_chunks_kernel(const int* __restrict__ chunksum,
                                                          int* __restrict__ chunkoff,
                                                          int* __restrict__ totalp) {
    __shared__ int s[NCHUNK];
    const int t = threadIdx.x;
    const int v = chunksum[t];
    s[t] = v;
    __syncthreads();
    for (int off = 1; off < NCHUNK; off <<= 1) {
        int add = (t >= off) ? s[t - off] : 0;
        __syncthreads();
        s[t] += add;
        __syncthreads();
    }
    chunkoff[t] = s[t] - v;            // exclusive prefix
    if (t == NCHUNK - 1) totalp[0] = s[t];
}

// K3: per-chunk LDS scan + write int idx spans. (settled in r5)
__global__ __launch_bounds__(256) void build_idx_kernel(const int* __restrict__ rep,
                                                        const int* __restrict__ chunkoff,
                                                        int* __restrict__ idx,
                                                        int S) {
    const int b = blockIdx.x;
    const int t = threadIdx.x;
    const int i = b * CHUNK + t;
    const int r = rep[i];
    __shared__ int s[CHUNK];
    s[t] = r;
    __syncthreads();
    for (int off = 1; off < CHUNK; off <<= 1) {
        int add = (t >= off) ? s[t - off] : 0;
        __syncthreads();
        s[t] += add;
        __syncthreads();
    }
    int end = chunkoff[b] + s[t];
    const int start = end - r;
    if (start >= S) return;
    if (end > S) end = S;
    for (int j = start; j < end; ++j) idx[j] = i;
}

// ---------------------------------------------------------------------------
// K4: gather. ROUND-6 CHANGE (single variable vs r5): FOUR output rows per
// wave, batching all 8 row-loads then all 8 row-stores — {8 KB read burst,
// 8 KB write burst} instead of per-row {2 KB, 2 KB} alternation (4x fewer
// machine-wide read/write turnarounds, 4x fewer dependent idx loads).
// nt stores KEPT: in this output-centric regime feeds is re-read ~3.5x
// through L3, and nt keeps the 512 MiB output stream from evicting it
// (r5-vs-r3 evidence: plain stores cost ~+28 us here). No swizzle, int idx.
// ---------------------------------------------------------------------------
__global__ __launch_bounds__(256) void gather_kernel(const f32x4* __restrict__ feeds,
                                                     const int* __restrict__ idx,
                                                     const int* __restrict__ totalp,
                                                     f32x4* __restrict__ out,
                                                     int S) {
    const int wave = (int)((blockIdx.x * blockDim.x + threadIdx.x) >> 6);
    const int lane = threadIdx.x & 63;
    const int j0 = wave * 4;              // first of 4 output rows
    if (j0 >= S) return;

    const int total = totalp[0];

    f32x4 a[4], b[4];
#pragma unroll
    for (int q = 0; q < 4; ++q) {
        const int j = j0 + q;
        if (j < total) {
            const int si = idx[j];
            const f32x4* src = feeds + (long long)si * D4;
            a[q] = src[lane];
            b[q] = src[lane + 64];
        } else {
            a[q] = (f32x4)0.f;
            b[q] = (f32x4)0.f;
        }
    }
#pragma unroll
    for (int q = 0; q < 4; ++q) {
        f32x4* dst = out + (long long)(j0 + q) * D4;
        __builtin_nontemporal_store(a[q], dst + lane);
        __builtin_nontemporal_store(b[q], dst + lane + 64);
    }
}

extern "C" void kernel_launch(void* const* d_in, const int* in_sizes, int n_in,
                              void* d_out, int out_size, void* d_ws, size_t ws_size,
                              hipStream_t stream) {
    const float* feeds = (const float*)d_in[0];
    const int*   rep   = (const int*)d_in[1];
    const int S = out_size / DCOLS;

    int* ws       = (int*)d_ws;
    int* chunksum = ws;            // 256 ints
    int* chunkoff = ws + 256;      // 256 ints
    int* totalp   = ws + 512;      // 1 int
    int* idx      = ws + 768;      // S ints = 1 MiB

    chunk_sum_kernel<<<NCHUNK, CHUNK, 0, stream>>>(rep, chunksum);
    scan_chunks_kernel<<<1, NCHUNK, 0, stream>>>(chunksum, chunkoff, totalp);
    build_idx_kernel<<<NCHUNK, CHUNK, 0, stream>>>(rep, chunkoff, idx, S);
    // Four output rows per wave: S/4 waves -> (S/4)*64 threads / 256 = S/16 blocks.
    gather_kernel<<<S / 16, 256, 0, stream>>>((const f32x4*)feeds, idx, totalp,
                                              (f32x4*)d_out, S);
}

// Round 7
// 593.313 us; speedup vs baseline: 1.0316x; 1.0316x over previous
//
#include <hip/hip_runtime.h>

// Problem constants (reference: N=65536, D=512, S=262144)
#define NROWS 65536
#define DCOLS 512
#define D4    128   // float4 per row
#define CHUNK 256   // rows per chunk
#define NCHUNK (NROWS / CHUNK)  // 256 chunks

typedef float f32x4 __attribute__((ext_vector_type(4)));

// ---------------------------------------------------------------------------
// FINAL CONFIGURATION — measured best (592 us, round 5). All axes isolated:
//   centricity: output-centric gather   (609/592 vs expand 630-640)
//   store policy: nontemporal           (protects L3-resident feeds reuse;
//                                        plain cost ~+28 us in this regime)
//   batching: 1 row/wave                (4-row batch +20 us w/ nt, r6)
//   scan: parallel 3-kernel             (-17 us vs single-block, r5)
//   fusion: separate kernels            (redundant-scan fusion +56 us, r4)
//
// Workspace layout (ints):
//   [0   .. 255]  chunksum[256]
//   [256 .. 511]  chunkoff[256]  (exclusive prefix of chunksum)
//   [512]         total
//   [768 .. ]     idx[S] (int, 1 MiB)
// ---------------------------------------------------------------------------

// K1: per-chunk sums of rep. 256 blocks x 256 threads.
__global__ __launch_bounds__(256) void chunk_sum_kernel(const int* __restrict__ rep,
                                                        int* __restrict__ chunksum) {
    const int b = blockIdx.x;
    const int t = threadIdx.x;
    int v = rep[b * CHUNK + t];
#pragma unroll
    for (int off = 32; off; off >>= 1) v += __shfl_down(v, off);
    __shared__ int ws4[4];
    if ((t & 63) == 0) ws4[t >> 6] = v;
    __syncthreads();
    if (t == 0) chunksum[b] = ws4[0] + ws4[1] + ws4[2] + ws4[3];
}

// K2: exclusive scan of 256 chunk sums + total. One tiny block.
__global__ __launch_bounds__(256) void scan_chunks_kernel(const int* __restrict__ chunksum,
                                                          int* __restrict__ chunkoff,
                                                          int* __restrict__ totalp) {
    __shared__ int s[NCHUNK];
    const int t = threadIdx.x;
    const int v = chunksum[t];
    s[t] = v;
    __syncthreads();
    for (int off = 1; off < NCHUNK; off <<= 1) {
        int add = (t >= off) ? s[t - off] : 0;
        __syncthreads();
        s[t] += add;
        __syncthreads();
    }
    chunkoff[t] = s[t] - v;            // exclusive prefix
    if (t == NCHUNK - 1) totalp[0] = s[t];
}

// K3: per-chunk LDS scan + write int idx spans. 256 blocks x 256 threads.
__global__ __launch_bounds__(256) void build_idx_kernel(const int* __restrict__ rep,
                                                        const int* __restrict__ chunkoff,
                                                        int* __restrict__ idx,
                                                        int S) {
    const int b = blockIdx.x;
    const int t = threadIdx.x;
    const int i = b * CHUNK + t;
    const int r = rep[i];
    __shared__ int s[CHUNK];
    s[t] = r;
    __syncthreads();
    for (int off = 1; off < CHUNK; off <<= 1) {
        int add = (t >= off) ? s[t - off] : 0;
        __syncthreads();
        s[t] += add;
        __syncthreads();
    }
    int end = chunkoff[b] + s[t];
    const int start = end - r;
    if (start >= S) return;
    if (end > S) end = S;
    for (int j = start; j < end; ++j) idx[j] = i;
}

// K4: gather. One wave per output row; nontemporal stores. Feeds is re-read
// ~3.5x through L3 in this structure; nt keeps the 512 MiB output stream
// from evicting it. 1 row/wave maximizes wave-level TLP over the dependent
// idx->row load chain (batched variants measured slower: r3 620, r6 612).
__global__ __launch_bounds__(256) void gather_kernel(const f32x4* __restrict__ feeds,
                                                     const int* __restrict__ idx,
                                                     const int* __restrict__ totalp,
                                                     f32x4* __restrict__ out,
                                                     int S) {
    const int wave = (int)((blockIdx.x * blockDim.x + threadIdx.x) >> 6);
    const int lane = threadIdx.x & 63;
    if (wave >= S) return;

    const int total = totalp[0];

    f32x4 a = (f32x4)0.f;
    f32x4 b = (f32x4)0.f;
    if (wave < total) {
        const int si = idx[wave];
        const f32x4* src = feeds + (long long)si * D4;
        a = src[lane];
        b = src[lane + 64];
    }
    f32x4* dst = out + (long long)wave * D4;
    __builtin_nontemporal_store(a, dst + lane);
    __builtin_nontemporal_store(b, dst + lane + 64);
}

extern "C" void kernel_launch(void* const* d_in, const int* in_sizes, int n_in,
                              void* d_out, int out_size, void* d_ws, size_t ws_size,
                              hipStream_t stream) {
    const float* feeds = (const float*)d_in[0];
    const int*   rep   = (const int*)d_in[1];
    const int S = out_size / DCOLS;

    int* ws       = (int*)d_ws;
    int* chunksum = ws;            // 256 ints
    int* chunkoff = ws + 256;      // 256 ints
    int* totalp   = ws + 512;      // 1 int
    int* idx      = ws + 768;      // S ints = 1 MiB

    chunk_sum_kernel<<<NCHUNK, CHUNK, 0, stream>>>(rep, chunksum);
    scan_chunks_kernel<<<1, NCHUNK, 0, stream>>>(chunksum, chunkoff, totalp);
    build_idx_kernel<<<NCHUNK, CHUNK, 0, stream>>>(rep, chunkoff, idx, S);
    // One wave per output row: S waves -> S*64 threads / 256 = S/4 blocks.
    gather_kernel<<<S / 4, 256, 0, stream>>>((const f32x4*)feeds, idx, totalp,
                                             (f32x4*)d_out, S);
}